// Round 13
// baseline (20.573 us; speedup 1.0000x reference)
//
#include <hip/hip_runtime.h>

// KAConv: out[b,f,h,w] = sum_{c,p} P_fcp(v) / (1 + |Q_fcp(v)|),
//   v = x[b,c,h+i-1,w+j-1] (zero pad), p = i*3+j
// Shapes: x[4,16,64,64], A[16,16,9,6], Bc[16,16,9,4], out[4,16,64,64], f32.
//
// Round 13 = r4 skeleton (best measured duty) + 3 compounding fixes:
//  (1) f-pairing: 2 output channels per block share the same window loads
//      (12 bounds-checked loads amortize over 432 math slots, ~20% stream cut)
//  (2) 4-way c-split (4 teams x 4 channels) -> 4 waves/SIMD TLP
//  (3) XCD-aligned indexing (XCD = rt): the 32 blocks sharing a row-slice of
//      x land on one XCD -> each x byte fetched once per L2 after the
//      harness's 268MB fill evicts caches every replay
//  c-loop unroll 1 (I$-resident ~7KB body); (1024,4) -> 128 VGPR cap, ~60
//  live, no spill (r12 had a 64-cap/75-live spill bug).

#define BB   4
#define CIN  16
#define COUT 16
#define HH   64
#define WW   64

__global__ __launch_bounds__(1024, 4) void KAConv_kernel(
    const float* __restrict__ x,    // [B,C,H,W]
    const float* __restrict__ A,    // [F,C,9,6]
    const float* __restrict__ Bc,   // [F,C,9,4]
    float* __restrict__ out)        // [B,F,H,W]
{
    // grid = fp(8) x b(4) x rt(8) = 256 blocks (1/CU); block = 1024 = 16 waves
    // = 4 teams x 4 waves; team t owns channels 4t..4t+3.
    const int blk = blockIdx.x;
    const int fp  = blk >> 5;            // f-pair 0..7
    const int b   = (blk >> 3) & 3;
    const int rt  = blk & 7;             // row-tile AND XCD id (blk%8 == rt)

    const int tid  = threadIdx.x;
    const int team = __builtin_amdgcn_readfirstlane(tid >> 8);   // 0..3
    const int tp   = tid & 255;
    const int w    = tp & 63;
    const int r0   = (rt << 3) + ((tp >> 6) << 1);   // rows r0, r0+1
    const int c0   = team << 2;                      // channels c0..c0+3
    const int f0   = fp << 1;                        // f0, f0+1

    const float* __restrict__ xb  = x  + (b * CIN + c0) * (HH * WW);
    const float* __restrict__ pA0 = A  + (f0 * CIN + c0) * 54;
    const float* __restrict__ pB0 = Bc + (f0 * CIN + c0) * 36;
    const float* __restrict__ pA1 = pA0 + CIN * 54;
    const float* __restrict__ pB1 = pB0 + CIN * 36;

    float acc00 = 0.0f, acc01 = 0.0f;    // f0: rows r0, r0+1
    float acc10 = 0.0f, acc11 = 0.0f;    // f1: rows r0, r0+1

    #pragma unroll 1
    for (int c = 0; c < 4; ++c) {
        const float* __restrict__ xc = xb + c * (HH * WW);

        // 4 window rows x 3 col offsets, zero-padded (shared by both f).
        float vv[4][3];
        #pragma unroll
        for (int ri = 0; ri < 4; ++ri) {
            const int hh   = r0 - 1 + ri;
            const bool okh = (hh >= 0) & (hh < HH);
            #pragma unroll
            for (int j = 0; j < 3; ++j) {
                const int wj  = w + j - 1;
                const bool ok = okh & (wj >= 0) & (wj < WW);
                vv[ri][j] = ok ? xc[hh * WW + wj] : 0.0f;
            }
        }

        const float* __restrict__ Ac0 = pA0 + c * 54;   // uniform -> s_load
        const float* __restrict__ Bq0 = pB0 + c * 36;
        const float* __restrict__ Ac1 = pA1 + c * 54;
        const float* __restrict__ Bq1 = pB1 + c * 36;

        #pragma unroll
        for (int p = 0; p < 9; ++p) {
            const int i = p / 3, j = p % 3;      // compile-time
            const float va = vv[i][j];
            const float vb = vv[i + 1][j];

            // ---- f0 ----
            {
                const float a0 = Ac0[p*6+0], a1 = Ac0[p*6+1], a2 = Ac0[p*6+2];
                const float a3 = Ac0[p*6+3], a4 = Ac0[p*6+4], a5 = Ac0[p*6+5];
                const float b1 = Bq0[p*4+0], b2 = Bq0[p*4+1];
                const float b3 = Bq0[p*4+2], b4 = Bq0[p*4+3];
                float P0 = a5, P1 = a5;
                P0 = fmaf(P0, va, a4);  P1 = fmaf(P1, vb, a4);
                P0 = fmaf(P0, va, a3);  P1 = fmaf(P1, vb, a3);
                P0 = fmaf(P0, va, a2);  P1 = fmaf(P1, vb, a2);
                P0 = fmaf(P0, va, a1);  P1 = fmaf(P1, vb, a1);
                P0 = fmaf(P0, va, a0);  P1 = fmaf(P1, vb, a0);
                float q0 = b4, q1 = b4;
                q0 = fmaf(q0, va, b3);  q1 = fmaf(q1, vb, b3);
                q0 = fmaf(q0, va, b2);  q1 = fmaf(q1, vb, b2);
                q0 = fmaf(q0, va, b1);  q1 = fmaf(q1, vb, b1);
                q0 *= va;               q1 *= vb;
                const float d0 = 1.0f + fabsf(q0);
                const float d1 = 1.0f + fabsf(q1);
                acc00 = fmaf(P0, __builtin_amdgcn_rcpf(d0), acc00);
                acc01 = fmaf(P1, __builtin_amdgcn_rcpf(d1), acc01);
            }
            // ---- f1 (same windows) ----
            {
                const float a0 = Ac1[p*6+0], a1 = Ac1[p*6+1], a2 = Ac1[p*6+2];
                const float a3 = Ac1[p*6+3], a4 = Ac1[p*6+4], a5 = Ac1[p*6+5];
                const float b1 = Bq1[p*4+0], b2 = Bq1[p*4+1];
                const float b3 = Bq1[p*4+2], b4 = Bq1[p*4+3];
                float P0 = a5, P1 = a5;
                P0 = fmaf(P0, va, a4);  P1 = fmaf(P1, vb, a4);
                P0 = fmaf(P0, va, a3);  P1 = fmaf(P1, vb, a3);
                P0 = fmaf(P0, va, a2);  P1 = fmaf(P1, vb, a2);
                P0 = fmaf(P0, va, a1);  P1 = fmaf(P1, vb, a1);
                P0 = fmaf(P0, va, a0);  P1 = fmaf(P1, vb, a0);
                float q0 = b4, q1 = b4;
                q0 = fmaf(q0, va, b3);  q1 = fmaf(q1, vb, b3);
                q0 = fmaf(q0, va, b2);  q1 = fmaf(q1, vb, b2);
                q0 = fmaf(q0, va, b1);  q1 = fmaf(q1, vb, b1);
                q0 *= va;               q1 *= vb;
                const float d0 = 1.0f + fabsf(q0);
                const float d1 = 1.0f + fabsf(q1);
                acc10 = fmaf(P0, __builtin_amdgcn_rcpf(d0), acc10);
                acc11 = fmaf(P1, __builtin_amdgcn_rcpf(d1), acc11);
            }
        }
    }

    // One barrier; 4-team reduction, all LDS ops stride-1 (conflict-free).
    __shared__ float sRed[4][4][256];    // [team][q][tp] = 16 KB
    sRed[team][0][tp] = acc00;
    sRed[team][1][tp] = acc01;
    sRed[team][2][tp] = acc10;
    sRed[team][3][tp] = acc11;
    __syncthreads();

    {
        const int q  = tid >> 8;         // 0..3: (f = q>>1, px = q&1)
        const int t2 = tid & 255;
        const float s = sRed[0][q][t2] + sRed[1][q][t2]
                      + sRed[2][q][t2] + sRed[3][q][t2];
        const int row = (rt << 3) + ((t2 >> 6) << 1) + (q & 1);
        const int f   = f0 + (q >> 1);
        const int col = t2 & 63;
        out[((b * COUT + f) * HH + row) * WW + col] = s;   // coalesced
    }
}

extern "C" void kernel_launch(void* const* d_in, const int* in_sizes, int n_in,
                              void* d_out, int out_size, void* d_ws, size_t ws_size,
                              hipStream_t stream) {
    const float* x  = (const float*)d_in[0];
    const float* A  = (const float*)d_in[1];
    const float* Bc = (const float*)d_in[2];
    float* out = (float*)d_out;

    const int grid = 8 * BB * 8;   // fp x b x rt = 256 blocks, 1/CU
    KAConv_kernel<<<grid, 1024, 0, stream>>>(x, A, Bc, out);
}

// Round 14
// 19.388 us; speedup vs baseline: 1.0611x; 1.0611x over previous
//
#include <hip/hip_runtime.h>

// KAConv: out[b,f,h,w] = sum_{c,p} P_fcp(v) / (1 + |Q_fcp(v)|),
//   v = x[b,c,h+i-1,w+j-1] (zero pad), p = i*3+j
// Shapes: x[4,16,64,64], A[16,16,9,6], Bc[16,16,9,4], out[4,16,64,64], f32.
//
// Round 14: long resident waves. wave = (f,c): the 90 coefficient dwords are
// wave-invariant (loaded once / sK$-hot — r8 proved zero scalar stalls), and
// the wave sweeps 16 output rows (8x r8's wave length, so r8's one-shot
// per-wave costs — load-burst wait, barrier, reduce, drain — drop to ~12%).
// Window rows roll through register triples with prefetch distance 1 row
// (~250 cy compute cover per load burst). 3 independent tap-row accumulators.
// No mid-kernel barriers; single 64KB LDS reduce, all stride-1 conflict-free.

#define BB   4
#define CIN  16
#define COUT 16
#define HH   64
#define WW   64

static __device__ __forceinline__ void loadrow(const float* __restrict__ xc,
                                               int hh, int w, float u[3]) {
    const bool okh = (hh >= 0) & (hh < HH);
    const float* __restrict__ rw = xc + hh * WW;
    u[0] = (okh & (w >= 1))      ? rw[w - 1] : 0.0f;
    u[1] = okh                   ? rw[w]     : 0.0f;
    u[2] = (okh & (w <= WW - 2)) ? rw[w + 1] : 0.0f;
}

__global__ __launch_bounds__(1024, 4) void KAConv_kernel(
    const float* __restrict__ x,    // [B,C,H,W]
    const float* __restrict__ A,    // [F,C,9,6]
    const float* __restrict__ Bc,   // [F,C,9,4]
    float* __restrict__ out)        // [B,F,H,W]
{
    // grid = b(4) x rg(4) x f(16) = 256 blocks (1/CU); block = 16 waves.
    const int blk = blockIdx.x;
    const int f   = blk & 15;
    const int rg  = (blk >> 4) & 3;
    const int b   = blk >> 6;

    const int tid   = threadIdx.x;
    const int c     = __builtin_amdgcn_readfirstlane(tid >> 6); // wave = channel
    const int w     = tid & 63;                                 // lane = column
    const int rbase = rg << 4;                                  // 16 rows

    const float* __restrict__ xc = x  + (b * CIN + c) * (HH * WW);
    const float* __restrict__ Ac = A  + (f * CIN + c) * 54;     // wave-invariant
    const float* __restrict__ Bq = Bc + (f * CIN + c) * 36;     // -> s_load once

    __shared__ float sRed[CIN][16][64];   // 64 KB partials

    // Rolling window rows: u0,u1,u2 = rows r-1, r, r+1; un = prefetch r+2.
    float u0[3], u1[3], u2[3];
    loadrow(xc, rbase - 1, w, u0);
    loadrow(xc, rbase,     w, u1);
    loadrow(xc, rbase + 1, w, u2);

#define TAP(p, v) {                                                         \
        float P = Ac[(p)*6+5];                                              \
        P = fmaf(P, (v), Ac[(p)*6+4]); P = fmaf(P, (v), Ac[(p)*6+3]);       \
        P = fmaf(P, (v), Ac[(p)*6+2]); P = fmaf(P, (v), Ac[(p)*6+1]);       \
        P = fmaf(P, (v), Ac[(p)*6+0]);                                      \
        float q = Bq[(p)*4+3];                                              \
        q = fmaf(q, (v), Bq[(p)*4+2]); q = fmaf(q, (v), Bq[(p)*4+1]);       \
        q = fmaf(q, (v), Bq[(p)*4+0]); q *= (v);                            \
        acc[(p)/3] = fmaf(P, __builtin_amdgcn_rcpf(1.0f + fabsf(q)),        \
                          acc[(p)/3]); }

    #pragma unroll 4
    for (int r = 0; r < 16; ++r) {
        // Prefetch row rbase+r+2 (used next iteration); bounds-clamped.
        float un[3];
        loadrow(xc, rbase + r + 2, w, un);

        // 9 taps on rows u0,u1,u2; 3 independent tap-row accumulators.
        float acc[3] = {0.0f, 0.0f, 0.0f};
        TAP(0, u0[0]) TAP(1, u0[1]) TAP(2, u0[2])
        TAP(3, u1[0]) TAP(4, u1[1]) TAP(5, u1[2])
        TAP(6, u2[0]) TAP(7, u2[1]) TAP(8, u2[2])
        sRed[c][r][w] = (acc[0] + acc[1]) + acc[2];   // stride-1: conflict-free

        // Rotate window rows.
        #pragma unroll
        for (int j = 0; j < 3; ++j) { u0[j] = u1[j]; u1[j] = u2[j]; u2[j] = un[j]; }
    }
#undef TAP

    __syncthreads();

    // 1024 threads -> 1024 outputs (16 rows x 64 cols), sum 16 channels.
    {
        const int row = tid >> 6;
        const int col = tid & 63;
        float s = 0.0f;
        #pragma unroll
        for (int k = 0; k < CIN; ++k) s += sRed[k][row][col];  // stride-1/instr
        out[((b * COUT + f) * HH + rbase + row) * WW + col] = s;  // coalesced
    }
}

extern "C" void kernel_launch(void* const* d_in, const int* in_sizes, int n_in,
                              void* d_out, int out_size, void* d_ws, size_t ws_size,
                              hipStream_t stream) {
    const float* x  = (const float*)d_in[0];
    const float* A  = (const float*)d_in[1];
    const float* Bc = (const float*)d_in[2];
    float* out = (float*)d_out;

    const int grid = BB * 4 * COUT;   // 256 blocks, 1 per CU
    KAConv_kernel<<<grid, 1024, 0, stream>>>(x, A, Bc, out);
}